// Round 1
// baseline (119.746 us; speedup 1.0000x reference)
//
#include <hip/hip_runtime.h>

// ROI align-style pooling (bilinear), matches reference _pool_one_roi exactly.
// img: (1,128,128,1024) f32, rois: (1,256,4) f32 (x,y,w,h in pixels)
// out: (1,256,7,7,1024) f32

#define IMG_H 128
#define IMG_W 128
#define IMG_C 1024
#define POOLK 7

__global__ __launch_bounds__(256) void roi_pool_kernel(
    const float* __restrict__ img,
    const float* __restrict__ rois,
    float* __restrict__ out) {
  const int ix = blockIdx.x;   // 0..6  (x position within 7x7 grid)
  const int iy = blockIdx.y;   // 0..6  (y position)
  const int r  = blockIdx.z;   // 0..255 (roi index)

  // All threads compute the (uniform) cell geometry redundantly — cheap.
  const float* roi = rois + (size_t)r * 4;
  const float rx = roi[0];
  const float ry = roi[1];
  const float rw = roi[2];
  const float rh = roi[3];

  // c = (roi * SCALE).astype(int32): values are non-negative, trunc == floor.
  const int x0 = (int)(rx * 0.0625f);
  const int y0 = (int)(ry * 0.0625f);
  const int w  = (int)(rw * 0.0625f);
  const int h  = (int)(rh * 0.0625f);

  // Match reference op order: (h_f / POOL) first, then multiply by i.
  const float step_y = (float)h / 7.0f;
  const float step_x = (float)w / 7.0f;
  const float sy = (float)iy * step_y;
  const float sx = (float)ix * step_x;
  const float fy = floorf(sy);
  const float fx = floorf(sx);
  const float ty = sy - fy;
  const float tx = sx - fx;
  const int y_lo = (int)fy;
  const int x_lo = (int)fx;
  const int y_hi = min(y_lo + 1, max(h - 1, 0));
  const int x_hi = min(x_lo + 1, max(w - 1, 0));
  const int gy0 = min(max(y0 + y_lo, 0), IMG_H - 1);
  const int gy1 = min(max(y0 + y_hi, 0), IMG_H - 1);
  const int gx0 = min(max(x0 + x_lo, 0), IMG_W - 1);
  const int gx1 = min(max(x0 + x_hi, 0), IMG_W - 1);

  const int c = threadIdx.x * 4;  // 256 threads x float4 = 1024 channels

  const size_t base00 = ((size_t)(gy0 * IMG_W + gx0)) * IMG_C + c;
  const size_t base01 = ((size_t)(gy0 * IMG_W + gx1)) * IMG_C + c;
  const size_t base10 = ((size_t)(gy1 * IMG_W + gx0)) * IMG_C + c;
  const size_t base11 = ((size_t)(gy1 * IMG_W + gx1)) * IMG_C + c;

  const float4 v00 = *(const float4*)(img + base00);
  const float4 v01 = *(const float4*)(img + base01);
  const float4 v10 = *(const float4*)(img + base10);
  const float4 v11 = *(const float4*)(img + base11);

  // top = v00 + tx*(v01-v00); bot = v10 + tx*(v11-v10); out = top + ty*(bot-top)
  float4 o;
  {
    float tpx = v00.x + tx * (v01.x - v00.x);
    float btx = v10.x + tx * (v11.x - v10.x);
    o.x = tpx + ty * (btx - tpx);
    float tpy = v00.y + tx * (v01.y - v00.y);
    float bty = v10.y + tx * (v11.y - v10.y);
    o.y = tpy + ty * (bty - tpy);
    float tpz = v00.z + tx * (v01.z - v00.z);
    float btz = v10.z + tx * (v11.z - v10.z);
    o.z = tpz + ty * (btz - tpz);
    float tpw = v00.w + tx * (v01.w - v00.w);
    float btw = v10.w + tx * (v11.w - v10.w);
    o.w = tpw + ty * (btw - tpw);
  }

  const size_t out_off =
      (((size_t)r * POOLK + iy) * POOLK + ix) * IMG_C + c;
  *(float4*)(out + out_off) = o;
}

extern "C" void kernel_launch(void* const* d_in, const int* in_sizes, int n_in,
                              void* d_out, int out_size, void* d_ws, size_t ws_size,
                              hipStream_t stream) {
  const float* img  = (const float*)d_in[0];   // 1*128*128*1024
  const float* rois = (const float*)d_in[1];   // 1*256*4
  float* out = (float*)d_out;                  // 1*256*7*7*1024

  dim3 grid(POOLK, POOLK, 256);
  dim3 block(256);
  roi_pool_kernel<<<grid, block, 0, stream>>>(img, rois, out);
}